// Round 19
// baseline (401.350 us; speedup 1.0000x reference)
//
#include <hip/hip_runtime.h>
#include <stdint.h>

#define HB 8
#define HL 128
#define HV 50257
#define HE 768
#define HM 400
#define HMT 800
#define HBL (HB*HL)
#define NTILES 393   // ceil(HV/128)
#define ELD 50272    // padded bf16-exp leading dim (mult of 16)
#define WTE_F4 ((long)HV*HE/4)   // 9,649,344
#define FCH 7        // finalize: chunks of 8192 cols per row

typedef __attribute__((ext_vector_type(4))) float f32x4;
typedef __attribute__((ext_vector_type(8))) short bf16x8;
typedef unsigned short u16;

struct u16x4 { u16 x, y, z, w; };

__device__ __forceinline__ u16 f2bf(float x){
  union { float f; uint32_t u; } v; v.f = x;
  uint32_t r = v.u + 0x7fffu + ((v.u >> 16) & 1u);
  return (u16)(r >> 16);
}
__device__ __forceinline__ float bf2f(u16 b){
  union { uint32_t u; float f; } v; v.u = ((uint32_t)b) << 16;
  return v.f;
}
__device__ __forceinline__ void glds(const u16* g, const u16* l){
  __builtin_amdgcn_global_load_lds(
      (const __attribute__((address_space(1))) void*)g,
      (__attribute__((address_space(3))) void*)l, 16, 0, 0);
}
// grid-stride f32->bf16 over f4 slice [lo4, lo4+n4), relb in [0,nb)
__device__ __forceinline__ void cvt_slice(const float* __restrict__ src,
    u16* __restrict__ dst, long lo4, long n4, int relb, int nb){
  long i = lo4 + (long)relb*256 + threadIdx.x;
  const long end = lo4 + n4;
  const long stride = (long)nb*256;
  for (; i < end; i += stride) {
    float4 x = ((const float4*)src)[i];
    u16x4 y; y.x=f2bf(x.x); y.y=f2bf(x.y); y.z=f2bf(x.z); y.w=f2bf(x.w);
    ((u16x4*)dst)[i] = y;
  }
}

// ---- merged: GCN scatter (b<384) + small-tensor prep (b<5840) + wte cvt ----
__global__ __launch_bounds__(256) void gcn_prep_k(const float* __restrict__ wte,
    const float* __restrict__ rel, const int* __restrict__ cids,
    const int* __restrict__ rids, const int* __restrict__ head,
    const int* __restrict__ tail, u16* __restrict__ An,
    const float* __restrict__ hs, const float* __restrict__ Wr1src,
    const float* __restrict__ Wt, const float* __restrict__ Ws1,
    const float* __restrict__ Wn1, const int* __restrict__ vmap,
    const int* __restrict__ mmask,
    u16* __restrict__ hid_b, u16* __restrict__ rel_b,
    u16* __restrict__ wr1, u16* __restrict__ wtT, u16* __restrict__ wcat,
    int* __restrict__ vmm, u16* __restrict__ wte_b){
  const int t = threadIdx.x;
  if (blockIdx.x >= 5840) {  // wte cvt slice 0: [0, 2621440)
    cvt_slice(wte, wte_b, 0, 2621440L, blockIdx.x - 5840, 2048);
    return;
  }
  if (blockIdx.x >= 384) {   // prep of small tensors
    const int b = blockIdx.x - 384;
    if (b < 768) {
      int i = b*256 + t;
      float4 x = ((const float4*)hs)[i];
      u16x4 y; y.x=f2bf(x.x); y.y=f2bf(x.y); y.z=f2bf(x.z); y.w=f2bf(x.w);
      ((u16x4*)hid_b)[i] = y;
    } else if (b < 798) {
      int i = (b-768)*256 + t;
      float4 x = ((const float4*)rel)[i];
      u16x4 y; y.x=f2bf(x.x); y.y=f2bf(x.y); y.z=f2bf(x.z); y.w=f2bf(x.w);
      ((u16x4*)rel_b)[i] = y;
    } else if (b < 1374) {
      int i = (b-798)*256 + t;
      float4 x = ((const float4*)Wr1src)[i];
      u16x4 y; y.x=f2bf(x.x); y.y=f2bf(x.y); y.z=f2bf(x.z); y.w=f2bf(x.w);
      ((u16x4*)wr1)[i] = y;
    } else if (b < 3102) {
      // coalesced LDS-tiled transpose: WtT[f][e] = Wt[e][f]
      __shared__ float tile[32][33];
      const int bp = b - 1374;          // 0..1727 = 24 e-tiles x 72 f-tiles
      const int tr = bp / 72;
      const int tc = bp - tr*72;
      const int e0 = tr*32, f0 = tc*32;
      const int i  = t >> 3;            // 0..31
      const int j4 = (t & 7) * 4;       // 0,4,..,28
      float4 x = *(const float4*)&Wt[(long)(e0 + i)*2304 + f0 + j4];
      tile[i][j4+0] = x.x; tile[i][j4+1] = x.y;
      tile[i][j4+2] = x.z; tile[i][j4+3] = x.w;
      __syncthreads();
      u16x4 y;
      y.x = f2bf(tile[j4+0][i]);
      y.y = f2bf(tile[j4+1][i]);
      y.z = f2bf(tile[j4+2][i]);
      y.w = f2bf(tile[j4+3][i]);
      *(u16x4*)&wtT[(long)(f0 + i)*HE + e0 + j4] = y;
    } else if (b < 5406) {
      int i = (b-3102)*256 + t;
      int e = i / HE, k = i - e*HE;
      wcat[(long)e*(2*HE) + k]      = f2bf(Ws1[i]);
      wcat[(long)e*(2*HE) + HE + k] = f2bf(Wn1[i]);
    } else {
      int base = (b-5406)*1024 + t*4;
      #pragma unroll
      for (int i = 0; i < 4; ++i) {
        int c = base + i;
        if (c < HV) vmm[c] = mmask[c] ? vmap[c] : -1;
      }
    }
    return;
  }
  // GCN scatter + anode build (per batch x 16-col chunk)
  const int ch = blockIdx.x % 48;
  const int b  = blockIdx.x / 48;
  const int e0 = ch * 16;
  __shared__ float cw[HM][17];
  __shared__ float upd[HM][17];
  __shared__ float relc[40][17];
  __shared__ float cnt[HM];
  const int tid = t;

  for (int idx = tid; idx < HM*16; idx += 256) {
    int m = idx >> 4, e = idx & 15;
    cw[m][e] = wte[(long)cids[b*HM+m]*HE + e0 + e];
    upd[m][e] = 0.f;
  }
  for (int idx = tid; idx < 40*16; idx += 256) {
    int r = idx >> 4, e = idx & 15;
    relc[r][e] = rel[r*HE + e0 + e];
  }
  for (int m = tid; m < HM; m += 256) cnt[m] = 0.f;
  __syncthreads();

  for (int j = tid; j < HMT; j += 256) {
    int h = head[b*HMT+j], tt = tail[b*HMT+j], r = rids[b*HMT+j];
    atomicAdd(&cnt[tt], 1.f);
    atomicAdd(&cnt[h], 1.f);
    #pragma unroll
    for (int e = 0; e < 16; ++e) {
      float rv = relc[r][e];
      atomicAdd(&upd[tt][e], cw[h][e] - rv);
      atomicAdd(&upd[h][e], cw[tt][e] - rv);
    }
  }
  __syncthreads();

  for (int idx = tid; idx < HM*16; idx += 256) {
    int m = idx >> 4, e = idx & 15;
    float ic = 1.f / fmaxf(cnt[m], 1.f);
    u16* dst = An + ((long)b*HM + m) * (2*HE);
    dst[e0 + e]      = f2bf(cw[m][e]);
    dst[HE + e0 + e] = f2bf(upd[m][e] * ic);
  }
}

// ---- MFMA GEMM core (small GEMMs): C[M,N] = act(A[M,K] @ B[N,K]^T) ---------
// 128x128 tile, BK=64, XOR-swizzled LDS, 4 waves 2x2, double-buffered with
// COUNTED vmcnt (T4).
template<int ACT, int OUTBF16, int DBUF>
__device__ __forceinline__ void gemm_core(
    const u16* __restrict__ Ab, const u16* __restrict__ Bb,
    void* __restrict__ Cout,
    int Mdim, int Ndim, int Kdim, int lda, int ldb, int ldc,
    int mtile, int ntile, u16* AsmB, u16* BsmB)
{
  const int m0 = mtile * 128;
  const int n0 = ntile * 128;
  const int tid = threadIdx.x;
  const int lane = tid & 63;
  const int wid = tid >> 6;
  const int wr = wid >> 1, wc = wid & 1;
  const int srw = lane >> 3;      // row within 8-row chunk
  const int sl  = lane & 7;       // 16B slot within 128B row

  f32x4 acc[4][4] = {};

  auto stage = [&](int buf, int k0) {   // 8 global_load_lds per thread
    u16* As = AsmB + buf*8192;
    u16* Bs = BsmB + buf*8192;
    #pragma unroll
    for (int i = 0; i < 4; ++i) {
      const int c = i*4 + wid;
      const int row = c*8 + srw;
      const int koff = k0 + ((sl ^ srw) * 8);
      int ra = m0 + row; if (ra > Mdim-1) ra = Mdim-1;
      glds(Ab + (long)ra * lda + koff, &As[c*512]);
      int rn = n0 + row; if (rn > Ndim-1) rn = Ndim-1;
      glds(Bb + (long)rn * ldb + koff, &Bs[c*512]);
    }
  };
  auto compute = [&](int buf) {
    const u16* As = AsmB + buf*8192;
    const u16* Bs = BsmB + buf*8192;
    #pragma unroll
    for (int kk = 0; kk < 2; ++kk) {
      bf16x8 af[4], bfr[4];
      #pragma unroll
      for (int mi = 0; mi < 4; ++mi) {
        const int R = wr*64 + mi*16 + (lane & 15);
        af[mi] = *(const bf16x8*)&As[R*64 + (((kk*4 + (lane>>4)) ^ (R & 7)) * 8)];
      }
      #pragma unroll
      for (int ni = 0; ni < 4; ++ni) {
        const int R = wc*64 + ni*16 + (lane & 15);
        bfr[ni] = *(const bf16x8*)&Bs[R*64 + (((kk*4 + (lane>>4)) ^ (R & 7)) * 8)];
      }
      #pragma unroll
      for (int mi = 0; mi < 4; ++mi)
        #pragma unroll
        for (int ni = 0; ni < 4; ++ni)
          acc[mi][ni] = __builtin_amdgcn_mfma_f32_16x16x32_bf16(af[mi], bfr[ni], acc[mi][ni], 0, 0, 0);
    }
  };

  const int NT = Kdim >> 6;
  if (DBUF) {
    stage(0, 0);
    asm volatile("s_waitcnt vmcnt(0)" ::: "memory");
    __builtin_amdgcn_s_barrier();
    int cur = 0;
    for (int t = 0; t < NT; ++t) {
      if (t + 1 < NT) {
        stage(cur ^ 1, (t + 1) << 6);                 // 8 loads in flight
        asm volatile("s_waitcnt vmcnt(8)" ::: "memory"); // own cur loads landed
      } else {
        asm volatile("s_waitcnt vmcnt(0)" ::: "memory");
      }
      __builtin_amdgcn_s_barrier();                    // ALL threads' cur landed
      compute(cur);
      __builtin_amdgcn_s_barrier();                    // all done reading cur
      cur ^= 1;
    }
  } else {
    for (int t = 0; t < NT; ++t) {
      stage(0, t << 6);
      __syncthreads();
      compute(0);
      __syncthreads();
    }
  }

  const int cr0 = m0 + wr*64 + ((lane >> 4) * 4);
  const int cc0 = n0 + wc*64 + (lane & 15);
  #pragma unroll
  for (int mi = 0; mi < 4; ++mi) {
    #pragma unroll
    for (int ni = 0; ni < 4; ++ni) {
      const int col = cc0 + ni*16;
      if (col < Ndim) {
        #pragma unroll
        for (int r = 0; r < 4; ++r) {
          const int rowi = cr0 + mi*16 + r;
          if (rowi < Mdim) {
            float v = acc[mi][ni][r];
            if (ACT == 1) v = fmaxf(v, 0.f);
            if (OUTBF16) ((u16*)Cout)[(long)rowi*ldc + col] = f2bf(v);
            else        ((float*)Cout)[(long)rowi*ldc + col] = v;
          }
        }
      }
    }
  }
}

// ---- dedicated big GEMM: exp(hid @ wte^T) + rowsum partials ----------------
// ROUND-13 WINNER: BK=32, 2 LDS bufs (32KB), counted vmcnt(4) pipeline,
// XOR-swizzled LDS (slot ^ (row>>1)&3, 0 conflicts), swapped-operand
// 16x16x32 MFMA -> lane holds 4 consecutive output cols -> ushort4 stores.
// Runtime dims (r9 lesson). 151us measured.
template<int EXPBF>
__global__ __launch_bounds__(256) void gemm_big(
    const u16* __restrict__ A, const u16* __restrict__ Bm,
    void* __restrict__ Cout, float* __restrict__ rowpart,
    int Mdim, int Ndim, int Kdim, int lda, int ldb, int ldc)
{
  __shared__ alignas(16) u16 Asm[2*4096];   // 2 bufs x 128x32
  __shared__ alignas(16) u16 Bsm[2*4096];
  const int wg = (blockIdx.x & 7) * NTILES + (blockIdx.x >> 3);
  const int m0 = (wg & 7) * 128;
  const int n0 = (wg >> 3) * 128;
  const int ntile = wg >> 3;
  const int tid = threadIdx.x;
  const int lane = tid & 63;
  const int wid = tid >> 6;
  const int wr = wid >> 1, wc = wid & 1;
  const int srow = lane >> 2;     // row within 16-row chunk
  const int sl = lane & 3;        // 16B slot within 64B row

  f32x4 acc[4][4] = {};           // [ni][mi]

  auto stage = [&](int buf, int k0) {   // 4 global_load_lds per thread
    u16* As = Asm + buf*4096;
    u16* Bs = Bsm + buf*4096;
    const int koff = k0 + ((sl ^ ((srow >> 1) & 3)) * 8);  // inverse-swizzled src
    #pragma unroll
    for (int i = 0; i < 2; ++i) {
      const int c = i*4 + wid;              // chunk 0..7, 16 rows each
      const int row = c*16 + srow;          // 0..127
      int ra = m0 + row; if (ra > Mdim-1) ra = Mdim-1;
      glds(A + (long)ra*lda + koff, &As[c*512]);
      int rn = n0 + row; if (rn > Ndim-1) rn = Ndim-1;
      glds(Bm + (long)rn*ldb + koff, &Bs[c*512]);
    }
  };
  auto compute = [&](int buf) {
    const u16* As = Asm + buf*4096;
    const u16* Bs = Bsm + buf*4096;
    bf16x8 af[4], bfr[4];
    #pragma unroll
    for (int mi = 0; mi < 4; ++mi) {
      const int R = wr*64 + mi*16 + (lane & 15);
      af[mi] = *(const bf16x8*)&As[R*32 + (((lane>>4) ^ ((R >> 1) & 3)) * 8)];
    }
    #pragma unroll
    for (int ni = 0; ni < 4; ++ni) {
      const int R = wc*64 + ni*16 + (lane & 15);
      bfr[ni] = *(const bf16x8*)&Bs[R*32 + (((lane>>4) ^ ((R >> 1) & 3)) * 8)];
    }
    #pragma unroll
    for (int ni = 0; ni < 4; ++ni)
      #pragma unroll
      for (int mi = 0; mi < 4; ++mi)
        acc[ni][mi] = __builtin_amdgcn_mfma_f32_16x16x32_bf16(bfr[ni], af[mi], acc[ni][mi], 0, 0, 0);
  };

  const int NT = Kdim >> 5;   // 24
  stage(0, 0);
  asm volatile("s_waitcnt vmcnt(0)" ::: "memory");
  __builtin_amdgcn_s_barrier();
  int cur = 0;
  for (int t = 0; t < NT; ++t) {
    if (t + 1 < NT) {
      stage(cur ^ 1, (t + 1) << 5);                  // 4 loads in flight
      asm volatile("s_waitcnt vmcnt(4)" ::: "memory"); // own cur loads landed
    } else {
      asm volatile("s_waitcnt vmcnt(0)" ::: "memory");
    }
    __builtin_amdgcn_s_barrier();                     // ALL threads' cur landed
    compute(cur);
    __builtin_amdgcn_s_barrier();                     // all done reading cur
    cur ^= 1;
  }

  // epilogue: swapped layout -> lane holds rows (wr*64+mi*16+f), cols
  // (wc*64+ni*16+g*4 .. +3), f=lane&15, g=lane>>4.
  const int f = lane & 15;
  float* rs = (float*)Asm;
  #pragma unroll
  for (int mi = 0; mi < 4; ++mi) {
    const int rowi = m0 + wr*64 + mi*16 + f;
    float s = 0.f;
    #pragma unroll
    for (int ni = 0; ni < 4; ++ni) {
      const int cb = n0 + wc*64 + ni*16 + (lane >> 4)*4;
      f32x4 a = acc[ni][mi];
      float e0 = __expf(a[0]), e1 = __expf(a[1]);
      float e2 = __expf(a[2]), e3 = __expf(a[3]);
      if (cb + 3 < Ndim) {
        s += e0 + e1 + e2 + e3;
        if (EXPBF) {
          ushort4 y; y.x=f2bf(e0); y.y=f2bf(e1); y.z=f2bf(e2); y.w=f2bf(e3);
          *(ushort4*)&((u16*)Cout)[(long)rowi*ldc + cb] = y;
        } else {
          float* dst = &((float*)Cout)[(long)rowi*ldc + cb];
          dst[0]=e0; dst[1]=e1; dst[2]=e2; dst[3]=e3;
        }
      } else {
        float ev[4] = {e0, e1, e2, e3};
        for (int i = 0; i < 4; ++i) {
          if (cb + i < Ndim) {
            s += ev[i];
            if (EXPBF) ((u16*)Cout)[(long)rowi*ldc + cb + i] = f2bf(ev[i]);
            else      ((float*)Cout)[(long)rowi*ldc + cb + i] = ev[i];
          }
        }
      }
    }
    s += __shfl_xor(s, 16);
    s += __shfl_xor(s, 32);
    if ((lane >> 4) == 0) rs[wc*128 + wr*64 + mi*16 + f] = s;
  }
  __syncthreads();
  if (tid < 128)
    rowpart[(long)(m0 + tid) * NTILES + ntile] = rs[tid] + rs[128 + tid];
}

// ---- multi0: node x8 + relWr + hw + wte-cvt slice 1 ------------------------
__global__ __launch_bounds__(256) void gemm_multi0(
    const u16* __restrict__ anode, const u16* __restrict__ wcat,
    u16* __restrict__ nodeb, const u16* __restrict__ rel_b,
    const u16* __restrict__ wr1, u16* __restrict__ relWr,
    const u16* __restrict__ hid_b, const u16* __restrict__ wtT,
    u16* __restrict__ hw, const float* __restrict__ wte,
    u16* __restrict__ wte_b)
{
  if (blockIdx.x >= 342) {   // wte cvt slice 1: [2621440, 6815744)
    cvt_slice(wte, wte_b, 2621440L, 4194304L, blockIdx.x - 342, 4096);
    return;
  }
  __shared__ alignas(16) u16 Asm[2*8192];
  __shared__ alignas(16) u16 Bsm[2*8192];
  const int q = blockIdx.x;
  if (q < 192) {
    const int z = q / 24, r = q - z*24;
    gemm_core<1,1,1>(anode + (long)z*HM*2*HE, wcat, nodeb + (long)z*HM*HE,
        HM, HE, 2*HE, 2*HE, 2*HE, HE, r & 3, r >> 2, Asm, Bsm);
  } else if (q < 198) {
    gemm_core<0,1,1>(rel_b, wr1, relWr,
        40, HE, HE, HE, HE, HE, 0, q - 192, Asm, Bsm);
  } else {
    const int u = q - 198;
    gemm_core<0,1,1>(hid_b, wtT, hw,
        HBL, 3*HE, HE, HE, HE, 3*HE, u & 7, u >> 3, Asm, Bsm);
  }
}

// ---- multi1: scores1/scores3/scoresR + wte-cvt slice 2 ---------------------
__global__ __launch_bounds__(256) void gemm_multi1(
    const u16* __restrict__ hw, const u16* __restrict__ nodeb,
    const u16* __restrict__ relWr, float* __restrict__ scores,
    const float* __restrict__ wte, u16* __restrict__ wte_b)
{
  if (blockIdx.x >= 72) {    // wte cvt slice 2: [6815744, 8388608)
    cvt_slice(wte, wte_b, 6815744L, 1572864L, blockIdx.x - 72, 1536);
    return;
  }
  __shared__ alignas(16) u16 Asm[2*8192];
  __shared__ alignas(16) u16 Bsm[2*8192];
  const int q = blockIdx.x;
  if (q < 32) {
    const int z = q >> 2;
    gemm_core<0,0,1>(hw + (long)z*HL*(3*HE), nodeb + (long)z*HM*HE,
        scores + (long)z*HL*840,
        HL, HM, HE, 3*HE, HE, 840, 0, q & 3, Asm, Bsm);
  } else if (q < 64) {
    const int z = (q - 32) >> 2;
    gemm_core<0,0,1>(hw + (long)z*HL*(3*HE) + 2*HE, nodeb + (long)z*HM*HE,
        scores + (long)z*HL*840 + HM,
        HL, HM, HE, 3*HE, HE, 840, 0, (q - 32) & 3, Asm, Bsm);
  } else {
    gemm_core<0,0,1>(hw + HE, relWr, scores + 2*HM,
        HBL, 40, HE, 3*HE, HE, 840, q - 64, 0, Asm, Bsm);
  }
}

// ---- multi-hop + gate + wte-cvt slice 3 ------------------------------------
__global__ __launch_bounds__(256) void multihop_k(const float* __restrict__ scores,
    const float* __restrict__ hs, const float* __restrict__ gw,
    const float* __restrict__ gb,
    const int* __restrict__ head, const int* __restrict__ tail,
    const int* __restrict__ rids, const int* __restrict__ labels,
    const int* __restrict__ dist, float* __restrict__ gatev,
    float* __restrict__ cprob, const float* __restrict__ wte,
    u16* __restrict__ wte_b){
  if (blockIdx.x >= HBL) {   // wte cvt slice 3: [8388608, 9649344)
    cvt_slice(wte, wte_b, 8388608L, WTE_F4 - 8388608L, blockIdx.x - HBL, 1280);
    return;
  }
  const int bl = blockIdx.x;
  const int b = bl >> 7;
  const int tid = threadIdx.x;
  const int lane = tid & 63, wid = tid >> 6;
  __shared__ float srow[840];
  __shared__ float tp[HMT];
  __shared__ float ns[HM], sacc[HM], tot[HM], invc[HM], dec[HM];
  __shared__ float red[16];
  __shared__ float gred[4];
  const int* hb = head + b*HMT;
  const int* tb = tail + b*HMT;
  const int* rb = rids + b*HMT;
  const int* lb = labels + b*HMT;
  const float* sr = scores + (long)bl * 840;

  float gs = 0.f;
  for (int e = tid; e < HE; e += 256) gs += hs[(long)bl*HE + e] * gw[e];
  for (int o = 32; o; o >>= 1) gs += __shfl_down(gs, o);
  if (lane == 0) gred[wid] = gs;

  for (int i = tid; i < 840; i += 256) srow[i] = sr[i];
  for (int m = tid; m < HM; m += 256) {
    int d = dist[b*HM + m];
    float im = (d == 0) ? 1.f : 0.f;
    ns[m] = im; tot[m] = im * -100000.f;
    dec[m] = (d == 0) ? 1.f : ((d == 1) ? 0.8f : 0.64f);
    sacc[m] = 0.f; invc[m] = 0.f;
  }
  __syncthreads();
  if (tid == 0)
    gatev[bl] = 1.f / (1.f + __expf(-(gred[0]+gred[1]+gred[2]+gred[3] + gb[0])));
  for (int j = tid; j < HMT; j += 256) {
    atomicAdd(&invc[tb[j]], 1.f);
    float x = srow[hb[j]] + srow[HM + tb[j]] + srow[2*HM + rb[j]];
    tp[j] = (lb[j] == -1) ? 0.f : 1.f / (1.f + __expf(-x));
  }
  __syncthreads();
  for (int m = tid; m < HM; m += 256) invc[m] = 1.f / fmaxf(invc[m], 1.f);
  __syncthreads();

  for (int hop = 0; hop < 2; ++hop) {
    for (int j = tid; j < HMT; j += 256) {
      float u = ns[hb[j]] * 0.8f + tp[j];
      atomicAdd(&sacc[tb[j]], u);
    }
    __syncthreads();
    for (int m = tid; m < HM; m += 256) {
      float v = sacc[m] * invc[m];
      ns[m] = v; tot[m] += v * dec[m]; sacc[m] = 0.f;
    }
    __syncthreads();
  }

  float lmx = -3.4e38f;
  for (int m = tid; m < HM; m += 256) lmx = fmaxf(lmx, tot[m]);
  for (int o = 32; o; o >>= 1) lmx = fmaxf(lmx, __shfl_down(lmx, o));
  if (lane == 0) red[wid] = lmx;
  __syncthreads();
  float gmx = fmaxf(fmaxf(red[0], red[1]), fmaxf(red[2], red[3]));
  float ls = 0.f;
  for (int m = tid; m < HM; m += 256) ls += __expf(tot[m] - gmx);
  for (int o = 32; o; o >>= 1) ls += __shfl_down(ls, o);
  if (lane == 0) red[8 + wid] = ls;
  __syncthreads();
  float inv = 1.f / (red[8] + red[9] + red[10] + red[11]);
  float* outrow = cprob + (long)bl * HM;
  for (int m = tid; m < HM; m += 256) outrow[m] = __expf(tot[m] - gmx) * inv;
}

// ---- finalize: fused rowsum reduce + LDS-gather blend ----------------------
// grid = HBL*FCH; per block: one row x 8192-col chunk, 16 elems/thread x2.
template<int EXPBF>
__global__ __launch_bounds__(256) void finalize_k(const void* __restrict__ expl,
    const float* __restrict__ rowpart, const float* __restrict__ gatev,
    const float* __restrict__ cprob, const int* __restrict__ vmm,
    float* __restrict__ out){
  const int r = blockIdx.x / FCH;
  const int ch = blockIdx.x - r*FCH;
  const int tid = threadIdx.x;
  __shared__ float red[4];
  __shared__ float cpl[HM];
  float s = 0.f;
  for (int t = tid; t < NTILES; t += 256) s += rowpart[r*NTILES + t];
  for (int o = 32; o; o >>= 1) s += __shfl_down(s, o);
  if ((tid & 63) == 0) red[tid >> 6] = s;
  const float g = gatev[r];
  for (int m = tid; m < HM; m += 256) cpl[m] = g * cprob[r*HM + m];
  __syncthreads();
  const float scale = (1.f - g) / (red[0] + red[1] + red[2] + red[3]);
  const u16* erb = (const u16*)expl + (long)r * ELD;
  const float* erf = (const float*)expl + (long)r * HV;
  float* orow = out + (long)r * HV;
  #pragma unroll
  for (int it = 0; it < 2; ++it) {
    const int c = ch*8192 + it*4096 + tid*16;
    if (c + 16 <= HV) {
      float e[16];
      if (EXPBF) {
        bf16x8 v0 = *(const bf16x8*)&erb[c];
        bf16x8 v1 = *(const bf16x8*)&erb[c+8];
        #pragma unroll
        for (int i = 0; i < 8; ++i) { e[i] = bf2f((u16)v0[i]); e[8+i] = bf2f((u16)v1[i]); }
      } else {
        #pragma unroll
        for (int p = 0; p < 4; ++p) {
          float4 a = *(const float4*)&erf[c + p*4];
          e[p*4+0]=a.x; e[p*4+1]=a.y; e[p*4+2]=a.z; e[p*4+3]=a.w;
        }
      }
      int ix[16];
      #pragma unroll
      for (int p = 0; p < 4; ++p) {
        int4 w = *(const int4*)&vmm[c + p*4];
        ix[p*4+0]=w.x; ix[p*4+1]=w.y; ix[p*4+2]=w.z; ix[p*4+3]=w.w;
      }
      float o16[16];
      #pragma unroll
      for (int i = 0; i < 16; ++i)
        o16[i] = (ix[i] >= 0 ? cpl[ix[i]] : 0.f) + scale * e[i];
      #pragma unroll
      for (int p = 0; p < 4; ++p)
        *(float4*)&orow[c + p*4] = make_float4(o16[p*4], o16[p*4+1], o16[p*4+2], o16[p*4+3]);
    } else if (c < HV) {
      for (int i = 0; i < 16 && c + i < HV; ++i) {
        float e = EXPBF ? bf2f(((const u16*)expl)[(long)r*ELD + c + i]) : erf[c+i];
        int ix = vmm[c+i];
        orow[c+i] = (ix >= 0 ? cpl[ix] : 0.f) + scale * e;
      }
    }
  }
}

// ---------------------------------------------------------------------------
extern "C" void kernel_launch(void* const* d_in, const int* in_sizes, int n_in,
                              void* d_out, int out_size, void* d_ws, size_t ws_size,
                              hipStream_t stream)
{
  const float* hs   = (const float*)d_in[0];
  const float* wte  = (const float*)d_in[1];
  const float* rel  = (const float*)d_in[2];
  const float* Ws   = (const float*)d_in[3];
  const float* Wn   = (const float*)d_in[4];
  const float* Wr   = (const float*)d_in[5];
  const float* Wt   = (const float*)d_in[6];
  const float* gw   = (const float*)d_in[7];
  const float* gb   = (const float*)d_in[8];
  const int* cids   = (const int*)d_in[9];
  const int* rids   = (const int*)d_in[10];
  const int* head   = (const int*)d_in[11];
  const int* tail   = (const int*)d_in[12];
  const int* labels = (const int*)d_in[13];
  const int* dist   = (const int*)d_in[14];
  const int* vmap   = (const int*)d_in[15];
  const int* mmask  = (const int*)d_in[16];
  float* out = (float*)d_out;

  char* ws = (char*)d_ws;
  size_t o = 0;
  auto alloc = [&](size_t bytes) -> char* {
    char* p = ws + o; o = (o + bytes + 255) & ~(size_t)255; return p;
  };
  // fixed region (live across the whole call)
  u16* wte_b     = (u16*)alloc((size_t)HV*HE*2);        // 77.2 MB
  u16* hid_b     = (u16*)alloc((size_t)HBL*HE*2);       // 1.6 MB
  float* cprob   = (float*)alloc((size_t)HBL*HM*4);     // 1.6 MB
  float* rowpart = (float*)alloc((size_t)HBL*NTILES*4); // 1.6 MB
  float* gatev   = (float*)alloc(HBL*4);
  int* vmm       = (int*)alloc((size_t)HV*4);           // 0.2 MB
  float* scores  = (float*)alloc((size_t)HBL*840*4);    // 3.4 MB

  // expl (bf16 exp of logits) aliases buffers dead before the big GEMM.
  const bool bigws = ws_size >= (size_t)196*1024*1024;
  u16* expl = (u16*)(ws + o);                           // 103.0 MB if bigws
  // union region (same offset as expl) — all dead after multihop_k
  u16* wcat  = (u16*)alloc((size_t)HE*2*HE*2);          // 2.4 MB
  u16* wr1   = (u16*)alloc((size_t)HE*HE*2);            // 1.2 MB
  u16* wtT   = (u16*)alloc((size_t)3*HE*HE*2);          // 3.5 MB
  u16* rel_b = (u16*)alloc((size_t)40*HE*2);
  u16* anode = (u16*)alloc((size_t)HB*HM*2*HE*2);       // 9.8 MB
  u16* nodeb = (u16*)alloc((size_t)HB*HM*HE*2);         // 4.9 MB
  u16* relWr = (u16*)alloc((size_t)40*HE*2);
  u16* hw    = (u16*)alloc((size_t)HBL*3*HE*2);         // 4.7 MB
  (void)in_sizes; (void)n_in; (void)out_size;

  // 1. merged: GCN scatter + small-tensor prep + wte cvt slice 0
  gcn_prep_k<<<5840 + 2048, 256, 0, stream>>>(wte, rel, cids, rids, head,
      tail, anode, hs, Wr + (size_t)HE*HE, Wt, Ws + (size_t)HE*HE,
      Wn + (size_t)HE*HE, vmap, mmask,
      hid_b, rel_b, wr1, wtT, wcat, vmm, wte_b);

  // 2. node x8 + relWr + hw = hid @ Wt  (+ wte cvt slice 1)
  gemm_multi0<<<342 + 4096, 256, 0, stream>>>(anode, wcat, nodeb, rel_b, wr1,
      relWr, hid_b, wtT, hw, wte, wte_b);
  // 3. scores1/scores3/scoresR  (+ wte cvt slice 2)
  gemm_multi1<<<72 + 1536, 256, 0, stream>>>(hw, nodeb, relWr, scores,
      wte, wte_b);

  // 4. multi-hop + gate  (+ wte cvt slice 3)
  multihop_k<<<HBL + 1280, 256, 0, stream>>>(scores, hs, gw, gb, head, tail,
      rids, labels, dist, gatev, cprob, wte, wte_b);

  // 5. exp(hid @ wte^T) + rowsum partials. Grid 3144 = 8 XCDs x 393 n-tiles.
  if (bigws) {
    gemm_big<1><<<3144, 256, 0, stream>>>(hid_b, wte_b, expl, rowpart,
        HBL, HV, HE, HE, HE, ELD);
    finalize_k<1><<<HBL*FCH, 256, 0, stream>>>(expl, rowpart, gatev, cprob,
        vmm, out);
  } else {
    gemm_big<0><<<3144, 256, 0, stream>>>(hid_b, wte_b, out, rowpart,
        HBL, HV, HE, HE, HE, HV);
    finalize_k<0><<<HBL*FCH, 256, 0, stream>>>(out, rowpart, gatev, cprob,
        vmm, out);
  }
}

// Round 20
// 379.766 us; speedup vs baseline: 1.0568x; 1.0568x over previous
//
#include <hip/hip_runtime.h>
#include <stdint.h>

#define HB 8
#define HL 128
#define HV 50257
#define HE 768
#define HM 400
#define HMT 800
#define HBL (HB*HL)
#define NTILES 393   // ceil(HV/128)
#define ELD 50272    // padded bf16-exp leading dim (mult of 16)
#define WTE_F4 ((long)HV*HE/4)   // 9,649,344

typedef __attribute__((ext_vector_type(4))) float f32x4;
typedef __attribute__((ext_vector_type(8))) short bf16x8;
typedef unsigned short u16;

struct u16x4 { u16 x, y, z, w; };

__device__ __forceinline__ u16 f2bf(float x){
  union { float f; uint32_t u; } v; v.f = x;
  uint32_t r = v.u + 0x7fffu + ((v.u >> 16) & 1u);
  return (u16)(r >> 16);
}
__device__ __forceinline__ float bf2f(u16 b){
  union { uint32_t u; float f; } v; v.u = ((uint32_t)b) << 16;
  return v.f;
}
__device__ __forceinline__ void glds(const u16* g, const u16* l){
  __builtin_amdgcn_global_load_lds(
      (const __attribute__((address_space(1))) void*)g,
      (__attribute__((address_space(3))) void*)l, 16, 0, 0);
}
// grid-stride f32->bf16 over f4 slice [lo4, lo4+n4), relb in [0,nb)
__device__ __forceinline__ void cvt_slice(const float* __restrict__ src,
    u16* __restrict__ dst, long lo4, long n4, int relb, int nb){
  long i = lo4 + (long)relb*256 + threadIdx.x;
  const long end = lo4 + n4;
  const long stride = (long)nb*256;
  for (; i < end; i += stride) {
    float4 x = ((const float4*)src)[i];
    u16x4 y; y.x=f2bf(x.x); y.y=f2bf(x.y); y.z=f2bf(x.z); y.w=f2bf(x.w);
    ((u16x4*)dst)[i] = y;
  }
}

// ---- merged: GCN scatter (b<384) + small-tensor prep (b<5840) + wte cvt ----
__global__ __launch_bounds__(256) void gcn_prep_k(const float* __restrict__ wte,
    const float* __restrict__ rel, const int* __restrict__ cids,
    const int* __restrict__ rids, const int* __restrict__ head,
    const int* __restrict__ tail, u16* __restrict__ An,
    const float* __restrict__ hs, const float* __restrict__ Wr1src,
    const float* __restrict__ Wt, const float* __restrict__ Ws1,
    const float* __restrict__ Wn1, const int* __restrict__ vmap,
    const int* __restrict__ mmask,
    u16* __restrict__ hid_b, u16* __restrict__ rel_b,
    u16* __restrict__ wr1, u16* __restrict__ wtT, u16* __restrict__ wcat,
    int* __restrict__ vmm, u16* __restrict__ wte_b){
  const int t = threadIdx.x;
  if (blockIdx.x >= 5840) {  // wte cvt slice 0: [0, 2621440)
    cvt_slice(wte, wte_b, 0, 2621440L, blockIdx.x - 5840, 2048);
    return;
  }
  if (blockIdx.x >= 384) {   // prep of small tensors
    const int b = blockIdx.x - 384;
    if (b < 768) {
      int i = b*256 + t;
      float4 x = ((const float4*)hs)[i];
      u16x4 y; y.x=f2bf(x.x); y.y=f2bf(x.y); y.z=f2bf(x.z); y.w=f2bf(x.w);
      ((u16x4*)hid_b)[i] = y;
    } else if (b < 798) {
      int i = (b-768)*256 + t;
      float4 x = ((const float4*)rel)[i];
      u16x4 y; y.x=f2bf(x.x); y.y=f2bf(x.y); y.z=f2bf(x.z); y.w=f2bf(x.w);
      ((u16x4*)rel_b)[i] = y;
    } else if (b < 1374) {
      int i = (b-798)*256 + t;
      float4 x = ((const float4*)Wr1src)[i];
      u16x4 y; y.x=f2bf(x.x); y.y=f2bf(x.y); y.z=f2bf(x.z); y.w=f2bf(x.w);
      ((u16x4*)wr1)[i] = y;
    } else if (b < 3102) {
      // coalesced LDS-tiled transpose: WtT[f][e] = Wt[e][f]
      __shared__ float tile[32][33];
      const int bp = b - 1374;          // 0..1727 = 24 e-tiles x 72 f-tiles
      const int tr = bp / 72;
      const int tc = bp - tr*72;
      const int e0 = tr*32, f0 = tc*32;
      const int i  = t >> 3;            // 0..31
      const int j4 = (t & 7) * 4;       // 0,4,..,28
      float4 x = *(const float4*)&Wt[(long)(e0 + i)*2304 + f0 + j4];
      tile[i][j4+0] = x.x; tile[i][j4+1] = x.y;
      tile[i][j4+2] = x.z; tile[i][j4+3] = x.w;
      __syncthreads();
      u16x4 y;
      y.x = f2bf(tile[j4+0][i]);
      y.y = f2bf(tile[j4+1][i]);
      y.z = f2bf(tile[j4+2][i]);
      y.w = f2bf(tile[j4+3][i]);
      *(u16x4*)&wtT[(long)(f0 + i)*HE + e0 + j4] = y;
    } else if (b < 5406) {
      int i = (b-3102)*256 + t;
      int e = i / HE, k = i - e*HE;
      wcat[(long)e*(2*HE) + k]      = f2bf(Ws1[i]);
      wcat[(long)e*(2*HE) + HE + k] = f2bf(Wn1[i]);
    } else {
      int base = (b-5406)*1024 + t*4;
      #pragma unroll
      for (int i = 0; i < 4; ++i) {
        int c = base + i;
        if (c < HV) vmm[c] = mmask[c] ? vmap[c] : -1;
      }
    }
    return;
  }
  // GCN scatter + anode build (per batch x 16-col chunk)
  const int ch = blockIdx.x % 48;
  const int b  = blockIdx.x / 48;
  const int e0 = ch * 16;
  __shared__ float cw[HM][17];
  __shared__ float upd[HM][17];
  __shared__ float relc[40][17];
  __shared__ float cnt[HM];
  const int tid = t;

  for (int idx = tid; idx < HM*16; idx += 256) {
    int m = idx >> 4, e = idx & 15;
    cw[m][e] = wte[(long)cids[b*HM+m]*HE + e0 + e];
    upd[m][e] = 0.f;
  }
  for (int idx = tid; idx < 40*16; idx += 256) {
    int r = idx >> 4, e = idx & 15;
    relc[r][e] = rel[r*HE + e0 + e];
  }
  for (int m = tid; m < HM; m += 256) cnt[m] = 0.f;
  __syncthreads();

  for (int j = tid; j < HMT; j += 256) {
    int h = head[b*HMT+j], tt = tail[b*HMT+j], r = rids[b*HMT+j];
    atomicAdd(&cnt[tt], 1.f);
    atomicAdd(&cnt[h], 1.f);
    #pragma unroll
    for (int e = 0; e < 16; ++e) {
      float rv = relc[r][e];
      atomicAdd(&upd[tt][e], cw[h][e] - rv);
      atomicAdd(&upd[h][e], cw[tt][e] - rv);
    }
  }
  __syncthreads();

  for (int idx = tid; idx < HM*16; idx += 256) {
    int m = idx >> 4, e = idx & 15;
    float ic = 1.f / fmaxf(cnt[m], 1.f);
    u16* dst = An + ((long)b*HM + m) * (2*HE);
    dst[e0 + e]      = f2bf(cw[m][e]);
    dst[HE + e0 + e] = f2bf(upd[m][e] * ic);
  }
}

// ---- MFMA GEMM core (small GEMMs): C[M,N] = act(A[M,K] @ B[N,K]^T) ---------
// 128x128 tile, BK=64, XOR-swizzled LDS, 4 waves 2x2, double-buffered with
// COUNTED vmcnt (T4).
template<int ACT, int OUTBF16, int DBUF>
__device__ __forceinline__ void gemm_core(
    const u16* __restrict__ Ab, const u16* __restrict__ Bb,
    void* __restrict__ Cout,
    int Mdim, int Ndim, int Kdim, int lda, int ldb, int ldc,
    int mtile, int ntile, u16* AsmB, u16* BsmB)
{
  const int m0 = mtile * 128;
  const int n0 = ntile * 128;
  const int tid = threadIdx.x;
  const int lane = tid & 63;
  const int wid = tid >> 6;
  const int wr = wid >> 1, wc = wid & 1;
  const int srw = lane >> 3;      // row within 8-row chunk
  const int sl  = lane & 7;       // 16B slot within 128B row

  f32x4 acc[4][4] = {};

  auto stage = [&](int buf, int k0) {   // 8 global_load_lds per thread
    u16* As = AsmB + buf*8192;
    u16* Bs = BsmB + buf*8192;
    #pragma unroll
    for (int i = 0; i < 4; ++i) {
      const int c = i*4 + wid;
      const int row = c*8 + srw;
      const int koff = k0 + ((sl ^ srw) * 8);
      int ra = m0 + row; if (ra > Mdim-1) ra = Mdim-1;
      glds(Ab + (long)ra * lda + koff, &As[c*512]);
      int rn = n0 + row; if (rn > Ndim-1) rn = Ndim-1;
      glds(Bb + (long)rn * ldb + koff, &Bs[c*512]);
    }
  };
  auto compute = [&](int buf) {
    const u16* As = AsmB + buf*8192;
    const u16* Bs = BsmB + buf*8192;
    #pragma unroll
    for (int kk = 0; kk < 2; ++kk) {
      bf16x8 af[4], bfr[4];
      #pragma unroll
      for (int mi = 0; mi < 4; ++mi) {
        const int R = wr*64 + mi*16 + (lane & 15);
        af[mi] = *(const bf16x8*)&As[R*64 + (((kk*4 + (lane>>4)) ^ (R & 7)) * 8)];
      }
      #pragma unroll
      for (int ni = 0; ni < 4; ++ni) {
        const int R = wc*64 + ni*16 + (lane & 15);
        bfr[ni] = *(const bf16x8*)&Bs[R*64 + (((kk*4 + (lane>>4)) ^ (R & 7)) * 8)];
      }
      #pragma unroll
      for (int mi = 0; mi < 4; ++mi)
        #pragma unroll
        for (int ni = 0; ni < 4; ++ni)
          acc[mi][ni] = __builtin_amdgcn_mfma_f32_16x16x32_bf16(af[mi], bfr[ni], acc[mi][ni], 0, 0, 0);
    }
  };

  const int NT = Kdim >> 6;
  if (DBUF) {
    stage(0, 0);
    asm volatile("s_waitcnt vmcnt(0)" ::: "memory");
    __builtin_amdgcn_s_barrier();
    int cur = 0;
    for (int t = 0; t < NT; ++t) {
      if (t + 1 < NT) {
        stage(cur ^ 1, (t + 1) << 6);                 // 8 loads in flight
        asm volatile("s_waitcnt vmcnt(8)" ::: "memory"); // own cur loads landed
      } else {
        asm volatile("s_waitcnt vmcnt(0)" ::: "memory");
      }
      __builtin_amdgcn_s_barrier();                    // ALL threads' cur landed
      compute(cur);
      __builtin_amdgcn_s_barrier();                    // all done reading cur
      cur ^= 1;
    }
  } else {
    for (int t = 0; t < NT; ++t) {
      stage(0, t << 6);
      __syncthreads();
      compute(0);
      __syncthreads();
    }
  }

  const int cr0 = m0 + wr*64 + ((lane >> 4) * 4);
  const int cc0 = n0 + wc*64 + (lane & 15);
  #pragma unroll
  for (int mi = 0; mi < 4; ++mi) {
    #pragma unroll
    for (int ni = 0; ni < 4; ++ni) {
      const int col = cc0 + ni*16;
      if (col < Ndim) {
        #pragma unroll
        for (int r = 0; r < 4; ++r) {
          const int rowi = cr0 + mi*16 + r;
          if (rowi < Mdim) {
            float v = acc[mi][ni][r];
            if (ACT == 1) v = fmaxf(v, 0.f);
            if (OUTBF16) ((u16*)Cout)[(long)rowi*ldc + col] = f2bf(v);
            else        ((float*)Cout)[(long)rowi*ldc + col] = v;
          }
        }
      }
    }
  }
}

// ---- dedicated big GEMM: exp(hid @ wte^T) + rowsum partials ----------------
// ROUND-13 WINNER: BK=32, 2 LDS bufs (32KB), counted vmcnt(4) pipeline,
// XOR-swizzled LDS (slot ^ (row>>1)&3, 0 conflicts), swapped-operand
// 16x16x32 MFMA -> lane holds 4 consecutive output cols -> ushort4 stores.
// Runtime dims (r9 lesson). 151us measured.
template<int EXPBF>
__global__ __launch_bounds__(256) void gemm_big(
    const u16* __restrict__ A, const u16* __restrict__ Bm,
    void* __restrict__ Cout, float* __restrict__ rowpart,
    int Mdim, int Ndim, int Kdim, int lda, int ldb, int ldc)
{
  __shared__ alignas(16) u16 Asm[2*4096];   // 2 bufs x 128x32
  __shared__ alignas(16) u16 Bsm[2*4096];
  const int wg = (blockIdx.x & 7) * NTILES + (blockIdx.x >> 3);
  const int m0 = (wg & 7) * 128;
  const int n0 = (wg >> 3) * 128;
  const int ntile = wg >> 3;
  const int tid = threadIdx.x;
  const int lane = tid & 63;
  const int wid = tid >> 6;
  const int wr = wid >> 1, wc = wid & 1;
  const int srow = lane >> 2;     // row within 16-row chunk
  const int sl = lane & 3;        // 16B slot within 64B row

  f32x4 acc[4][4] = {};           // [ni][mi]

  auto stage = [&](int buf, int k0) {   // 4 global_load_lds per thread
    u16* As = Asm + buf*4096;
    u16* Bs = Bsm + buf*4096;
    const int koff = k0 + ((sl ^ ((srow >> 1) & 3)) * 8);  // inverse-swizzled src
    #pragma unroll
    for (int i = 0; i < 2; ++i) {
      const int c = i*4 + wid;              // chunk 0..7, 16 rows each
      const int row = c*16 + srow;          // 0..127
      int ra = m0 + row; if (ra > Mdim-1) ra = Mdim-1;
      glds(A + (long)ra*lda + koff, &As[c*512]);
      int rn = n0 + row; if (rn > Ndim-1) rn = Ndim-1;
      glds(Bm + (long)rn*ldb + koff, &Bs[c*512]);
    }
  };
  auto compute = [&](int buf) {
    const u16* As = Asm + buf*4096;
    const u16* Bs = Bsm + buf*4096;
    bf16x8 af[4], bfr[4];
    #pragma unroll
    for (int mi = 0; mi < 4; ++mi) {
      const int R = wr*64 + mi*16 + (lane & 15);
      af[mi] = *(const bf16x8*)&As[R*32 + (((lane>>4) ^ ((R >> 1) & 3)) * 8)];
    }
    #pragma unroll
    for (int ni = 0; ni < 4; ++ni) {
      const int R = wc*64 + ni*16 + (lane & 15);
      bfr[ni] = *(const bf16x8*)&Bs[R*32 + (((lane>>4) ^ ((R >> 1) & 3)) * 8)];
    }
    #pragma unroll
    for (int ni = 0; ni < 4; ++ni)
      #pragma unroll
      for (int mi = 0; mi < 4; ++mi)
        acc[ni][mi] = __builtin_amdgcn_mfma_f32_16x16x32_bf16(bfr[ni], af[mi], acc[ni][mi], 0, 0, 0);
  };

  const int NT = Kdim >> 5;   // 24
  stage(0, 0);
  asm volatile("s_waitcnt vmcnt(0)" ::: "memory");
  __builtin_amdgcn_s_barrier();
  int cur = 0;
  for (int t = 0; t < NT; ++t) {
    if (t + 1 < NT) {
      stage(cur ^ 1, (t + 1) << 5);                  // 4 loads in flight
      asm volatile("s_waitcnt vmcnt(4)" ::: "memory"); // own cur loads landed
    } else {
      asm volatile("s_waitcnt vmcnt(0)" ::: "memory");
    }
    __builtin_amdgcn_s_barrier();                     // ALL threads' cur landed
    compute(cur);
    __builtin_amdgcn_s_barrier();                     // all done reading cur
    cur ^= 1;
  }

  // epilogue: swapped layout -> lane holds rows (wr*64+mi*16+f), cols
  // (wc*64+ni*16+g*4 .. +3), f=lane&15, g=lane>>4.
  const int f = lane & 15;
  float* rs = (float*)Asm;
  #pragma unroll
  for (int mi = 0; mi < 4; ++mi) {
    const int rowi = m0 + wr*64 + mi*16 + f;
    float s = 0.f;
    #pragma unroll
    for (int ni = 0; ni < 4; ++ni) {
      const int cb = n0 + wc*64 + ni*16 + (lane >> 4)*4;
      f32x4 a = acc[ni][mi];
      float e0 = __expf(a[0]), e1 = __expf(a[1]);
      float e2 = __expf(a[2]), e3 = __expf(a[3]);
      if (cb + 3 < Ndim) {
        s += e0 + e1 + e2 + e3;
        if (EXPBF) {
          ushort4 y; y.x=f2bf(e0); y.y=f2bf(e1); y.z=f2bf(e2); y.w=f2bf(e3);
          *(ushort4*)&((u16*)Cout)[(long)rowi*ldc + cb] = y;
        } else {
          float* dst = &((float*)Cout)[(long)rowi*ldc + cb];
          dst[0]=e0; dst[1]=e1; dst[2]=e2; dst[3]=e3;
        }
      } else {
        float ev[4] = {e0, e1, e2, e3};
        for (int i = 0; i < 4; ++i) {
          if (cb + i < Ndim) {
            s += ev[i];
            if (EXPBF) ((u16*)Cout)[(long)rowi*ldc + cb + i] = f2bf(ev[i]);
            else      ((float*)Cout)[(long)rowi*ldc + cb + i] = ev[i];
          }
        }
      }
    }
    s += __shfl_xor(s, 16);
    s += __shfl_xor(s, 32);
    if ((lane >> 4) == 0) rs[wc*128 + wr*64 + mi*16 + f] = s;
  }
  __syncthreads();
  if (tid < 128)
    rowpart[(long)(m0 + tid) * NTILES + ntile] = rs[tid] + rs[128 + tid];
}

// ---- multi0: node x8 + relWr + hw + wte-cvt slice 1 ------------------------
__global__ __launch_bounds__(256) void gemm_multi0(
    const u16* __restrict__ anode, const u16* __restrict__ wcat,
    u16* __restrict__ nodeb, const u16* __restrict__ rel_b,
    const u16* __restrict__ wr1, u16* __restrict__ relWr,
    const u16* __restrict__ hid_b, const u16* __restrict__ wtT,
    u16* __restrict__ hw, const float* __restrict__ wte,
    u16* __restrict__ wte_b)
{
  if (blockIdx.x >= 342) {   // wte cvt slice 1: [2621440, 6815744)
    cvt_slice(wte, wte_b, 2621440L, 4194304L, blockIdx.x - 342, 4096);
    return;
  }
  __shared__ alignas(16) u16 Asm[2*8192];
  __shared__ alignas(16) u16 Bsm[2*8192];
  const int q = blockIdx.x;
  if (q < 192) {
    const int z = q / 24, r = q - z*24;
    gemm_core<1,1,1>(anode + (long)z*HM*2*HE, wcat, nodeb + (long)z*HM*HE,
        HM, HE, 2*HE, 2*HE, 2*HE, HE, r & 3, r >> 2, Asm, Bsm);
  } else if (q < 198) {
    gemm_core<0,1,1>(rel_b, wr1, relWr,
        40, HE, HE, HE, HE, HE, 0, q - 192, Asm, Bsm);
  } else {
    const int u = q - 198;
    gemm_core<0,1,1>(hid_b, wtT, hw,
        HBL, 3*HE, HE, HE, HE, 3*HE, u & 7, u >> 3, Asm, Bsm);
  }
}

// ---- multi1: scores1/scores3/scoresR + wte-cvt slice 2 ---------------------
__global__ __launch_bounds__(256) void gemm_multi1(
    const u16* __restrict__ hw, const u16* __restrict__ nodeb,
    const u16* __restrict__ relWr, float* __restrict__ scores,
    const float* __restrict__ wte, u16* __restrict__ wte_b)
{
  if (blockIdx.x >= 72) {    // wte cvt slice 2: [6815744, 8388608)
    cvt_slice(wte, wte_b, 6815744L, 1572864L, blockIdx.x - 72, 1536);
    return;
  }
  __shared__ alignas(16) u16 Asm[2*8192];
  __shared__ alignas(16) u16 Bsm[2*8192];
  const int q = blockIdx.x;
  if (q < 32) {
    const int z = q >> 2;
    gemm_core<0,0,1>(hw + (long)z*HL*(3*HE), nodeb + (long)z*HM*HE,
        scores + (long)z*HL*840,
        HL, HM, HE, 3*HE, HE, 840, 0, q & 3, Asm, Bsm);
  } else if (q < 64) {
    const int z = (q - 32) >> 2;
    gemm_core<0,0,1>(hw + (long)z*HL*(3*HE) + 2*HE, nodeb + (long)z*HM*HE,
        scores + (long)z*HL*840 + HM,
        HL, HM, HE, 3*HE, HE, 840, 0, (q - 32) & 3, Asm, Bsm);
  } else {
    gemm_core<0,0,1>(hw + HE, relWr, scores + 2*HM,
        HBL, 40, HE, 3*HE, HE, 840, q - 64, 0, Asm, Bsm);
  }
}

// ---- multi-hop + gate + wte-cvt slice 3 ------------------------------------
__global__ __launch_bounds__(256) void multihop_k(const float* __restrict__ scores,
    const float* __restrict__ hs, const float* __restrict__ gw,
    const float* __restrict__ gb,
    const int* __restrict__ head, const int* __restrict__ tail,
    const int* __restrict__ rids, const int* __restrict__ labels,
    const int* __restrict__ dist, float* __restrict__ gatev,
    float* __restrict__ cprob, const float* __restrict__ wte,
    u16* __restrict__ wte_b){
  if (blockIdx.x >= HBL) {   // wte cvt slice 3: [8388608, 9649344)
    cvt_slice(wte, wte_b, 8388608L, WTE_F4 - 8388608L, blockIdx.x - HBL, 1280);
    return;
  }
  const int bl = blockIdx.x;
  const int b = bl >> 7;
  const int tid = threadIdx.x;
  const int lane = tid & 63, wid = tid >> 6;
  __shared__ float srow[840];
  __shared__ float tp[HMT];
  __shared__ float ns[HM], sacc[HM], tot[HM], invc[HM], dec[HM];
  __shared__ float red[16];
  __shared__ float gred[4];
  const int* hb = head + b*HMT;
  const int* tb = tail + b*HMT;
  const int* rb = rids + b*HMT;
  const int* lb = labels + b*HMT;
  const float* sr = scores + (long)bl * 840;

  float gs = 0.f;
  for (int e = tid; e < HE; e += 256) gs += hs[(long)bl*HE + e] * gw[e];
  for (int o = 32; o; o >>= 1) gs += __shfl_down(gs, o);
  if (lane == 0) gred[wid] = gs;

  for (int i = tid; i < 840; i += 256) srow[i] = sr[i];
  for (int m = tid; m < HM; m += 256) {
    int d = dist[b*HM + m];
    float im = (d == 0) ? 1.f : 0.f;
    ns[m] = im; tot[m] = im * -100000.f;
    dec[m] = (d == 0) ? 1.f : ((d == 1) ? 0.8f : 0.64f);
    sacc[m] = 0.f; invc[m] = 0.f;
  }
  __syncthreads();
  if (tid == 0)
    gatev[bl] = 1.f / (1.f + __expf(-(gred[0]+gred[1]+gred[2]+gred[3] + gb[0])));
  for (int j = tid; j < HMT; j += 256) {
    atomicAdd(&invc[tb[j]], 1.f);
    float x = srow[hb[j]] + srow[HM + tb[j]] + srow[2*HM + rb[j]];
    tp[j] = (lb[j] == -1) ? 0.f : 1.f / (1.f + __expf(-x));
  }
  __syncthreads();
  for (int m = tid; m < HM; m += 256) invc[m] = 1.f / fmaxf(invc[m], 1.f);
  __syncthreads();

  for (int hop = 0; hop < 2; ++hop) {
    for (int j = tid; j < HMT; j += 256) {
      float u = ns[hb[j]] * 0.8f + tp[j];
      atomicAdd(&sacc[tb[j]], u);
    }
    __syncthreads();
    for (int m = tid; m < HM; m += 256) {
      float v = sacc[m] * invc[m];
      ns[m] = v; tot[m] += v * dec[m]; sacc[m] = 0.f;
    }
    __syncthreads();
  }

  float lmx = -3.4e38f;
  for (int m = tid; m < HM; m += 256) lmx = fmaxf(lmx, tot[m]);
  for (int o = 32; o; o >>= 1) lmx = fmaxf(lmx, __shfl_down(lmx, o));
  if (lane == 0) red[wid] = lmx;
  __syncthreads();
  float gmx = fmaxf(fmaxf(red[0], red[1]), fmaxf(red[2], red[3]));
  float ls = 0.f;
  for (int m = tid; m < HM; m += 256) ls += __expf(tot[m] - gmx);
  for (int o = 32; o; o >>= 1) ls += __shfl_down(ls, o);
  if (lane == 0) red[8 + wid] = ls;
  __syncthreads();
  float inv = 1.f / (red[8] + red[9] + red[10] + red[11]);
  float* outrow = cprob + (long)bl * HM;
  for (int m = tid; m < HM; m += 256) outrow[m] = __expf(tot[m] - gmx) * inv;
}

// ---- finalize: fused rowsum reduce + LDS-gather blend ----------------------
// grid = HBL*13; per block: one row x 4096-col chunk, 8 elems/thread x2.
template<int EXPBF>
__global__ __launch_bounds__(256) void finalize_k(const void* __restrict__ expl,
    const float* __restrict__ rowpart, const float* __restrict__ gatev,
    const float* __restrict__ cprob, const int* __restrict__ vmm,
    float* __restrict__ out){
  const int r = blockIdx.x / 13;
  const int ch = blockIdx.x - r*13;
  const int tid = threadIdx.x;
  __shared__ float red[4];
  __shared__ float cpl[HM];
  float s = 0.f;
  for (int t = tid; t < NTILES; t += 256) s += rowpart[r*NTILES + t];
  for (int o = 32; o; o >>= 1) s += __shfl_down(s, o);
  if ((tid & 63) == 0) red[tid >> 6] = s;
  const float g = gatev[r];
  for (int m = tid; m < HM; m += 256) cpl[m] = g * cprob[r*HM + m];
  __syncthreads();
  const float scale = (1.f - g) / (red[0] + red[1] + red[2] + red[3]);
  const u16* erb = (const u16*)expl + (long)r * ELD;
  const float* erf = (const float*)expl + (long)r * HV;
  float* orow = out + (long)r * HV;
  #pragma unroll
  for (int it = 0; it < 2; ++it) {
    const int c = ch*4096 + it*2048 + tid*8;
    if (c + 8 <= HV) {
      float e[8];
      if (EXPBF) {
        bf16x8 v = *(const bf16x8*)&erb[c];
        #pragma unroll
        for (int i = 0; i < 8; ++i) e[i] = bf2f((u16)v[i]);
      } else {
        float4 a = *(const float4*)&erf[c];
        float4 b2 = *(const float4*)&erf[c+4];
        e[0]=a.x; e[1]=a.y; e[2]=a.z; e[3]=a.w;
        e[4]=b2.x; e[5]=b2.y; e[6]=b2.z; e[7]=b2.w;
      }
      int4 v0 = *(const int4*)&vmm[c];
      int4 v1 = *(const int4*)&vmm[c+4];
      const int ix[8] = {v0.x, v0.y, v0.z, v0.w, v1.x, v1.y, v1.z, v1.w};
      float o8[8];
      #pragma unroll
      for (int i = 0; i < 8; ++i)
        o8[i] = (ix[i] >= 0 ? cpl[ix[i]] : 0.f) + scale * e[i];
      *(float4*)&orow[c]   = make_float4(o8[0], o8[1], o8[2], o8[3]);
      *(float4*)&orow[c+4] = make_float4(o8[4], o8[5], o8[6], o8[7]);
    } else if (c < HV) {
      for (int i = 0; i < 8 && c + i < HV; ++i) {
        float e = EXPBF ? bf2f(((const u16*)expl)[(long)r*ELD + c + i]) : erf[c+i];
        int ix = vmm[c+i];
        orow[c+i] = (ix >= 0 ? cpl[ix] : 0.f) + scale * e;
      }
    }
  }
}

// ---------------------------------------------------------------------------
extern "C" void kernel_launch(void* const* d_in, const int* in_sizes, int n_in,
                              void* d_out, int out_size, void* d_ws, size_t ws_size,
                              hipStream_t stream)
{
  const float* hs   = (const float*)d_in[0];
  const float* wte  = (const float*)d_in[1];
  const float* rel  = (const float*)d_in[2];
  const float* Ws   = (const float*)d_in[3];
  const float* Wn   = (const float*)d_in[4];
  const float* Wr   = (const float*)d_in[5];
  const float* Wt   = (const float*)d_in[6];
  const float* gw   = (const float*)d_in[7];
  const float* gb   = (const float*)d_in[8];
  const int* cids   = (const int*)d_in[9];
  const int* rids   = (const int*)d_in[10];
  const int* head   = (const int*)d_in[11];
  const int* tail   = (const int*)d_in[12];
  const int* labels = (const int*)d_in[13];
  const int* dist   = (const int*)d_in[14];
  const int* vmap   = (const int*)d_in[15];
  const int* mmask  = (const int*)d_in[16];
  float* out = (float*)d_out;

  char* ws = (char*)d_ws;
  size_t o = 0;
  auto alloc = [&](size_t bytes) -> char* {
    char* p = ws + o; o = (o + bytes + 255) & ~(size_t)255; return p;
  };
  // fixed region (live across the whole call)
  u16* wte_b     = (u16*)alloc((size_t)HV*HE*2);        // 77.2 MB
  u16* hid_b     = (u16*)alloc((size_t)HBL*HE*2);       // 1.6 MB
  float* cprob   = (float*)alloc((size_t)HBL*HM*4);     // 1.6 MB
  float* rowpart = (float*)alloc((size_t)HBL*NTILES*4); // 1.6 MB
  float* gatev   = (float*)alloc(HBL*4);
  int* vmm       = (int*)alloc((size_t)HV*4);           // 0.2 MB
  float* scores  = (float*)alloc((size_t)HBL*840*4);    // 3.4 MB

  // expl (bf16 exp of logits) aliases buffers dead before the big GEMM.
  const bool bigws = ws_size >= (size_t)196*1024*1024;
  u16* expl = (u16*)(ws + o);                           // 103.0 MB if bigws
  // union region (same offset as expl) — all dead after multihop_k
  u16* wcat  = (u16*)alloc((size_t)HE*2*HE*2);          // 2.4 MB
  u16* wr1   = (u16*)alloc((size_t)HE*HE*2);            // 1.2 MB
  u16* wtT   = (u16*)alloc((size_t)3*HE*HE*2);          // 3.5 MB
  u16* rel_b = (u16*)alloc((size_t)40*HE*2);
  u16* anode = (u16*)alloc((size_t)HB*HM*2*HE*2);       // 9.8 MB
  u16* nodeb = (u16*)alloc((size_t)HB*HM*HE*2);         // 4.9 MB
  u16* relWr = (u16*)alloc((size_t)40*HE*2);
  u16* hw    = (u16*)alloc((size_t)HBL*3*HE*2);         // 4.7 MB
  (void)in_sizes; (void)n_in; (void)out_size;

  // 1. merged: GCN scatter + small-tensor prep + wte cvt slice 0
  gcn_prep_k<<<5840 + 2048, 256, 0, stream>>>(wte, rel, cids, rids, head,
      tail, anode, hs, Wr + (size_t)HE*HE, Wt, Ws + (size_t)HE*HE,
      Wn + (size_t)HE*HE, vmap, mmask,
      hid_b, rel_b, wr1, wtT, wcat, vmm, wte_b);

  // 2. node x8 + relWr + hw = hid @ Wt  (+ wte cvt slice 1)
  gemm_multi0<<<342 + 4096, 256, 0, stream>>>(anode, wcat, nodeb, rel_b, wr1,
      relWr, hid_b, wtT, hw, wte, wte_b);
  // 3. scores1/scores3/scoresR  (+ wte cvt slice 2)
  gemm_multi1<<<72 + 1536, 256, 0, stream>>>(hw, nodeb, relWr, scores,
      wte, wte_b);

  // 4. multi-hop + gate  (+ wte cvt slice 3)
  multihop_k<<<HBL + 1280, 256, 0, stream>>>(scores, hs, gw, gb, head, tail,
      rids, labels, dist, gatev, cprob, wte, wte_b);

  // 5. exp(hid @ wte^T) + rowsum partials. Grid 3144 = 8 XCDs x 393 n-tiles.
  if (bigws) {
    gemm_big<1><<<3144, 256, 0, stream>>>(hid_b, wte_b, expl, rowpart,
        HBL, HV, HE, HE, HE, ELD);
    finalize_k<1><<<HBL*13, 256, 0, stream>>>(expl, rowpart, gatev, cprob,
        vmm, out);
  } else {
    gemm_big<0><<<3144, 256, 0, stream>>>(hid_b, wte_b, out, rowpart,
        HBL, HV, HE, HE, HE, HV);
    finalize_k<0><<<HBL*13, 256, 0, stream>>>(out, rowpart, gatev, cprob,
        vmm, out);
  }
}